// Round 10
// baseline (245.565 us; speedup 1.0000x reference)
//
#include <hip/hip_runtime.h>
#include <math.h>

#define BB 2
#define NN 512
#define FF 64
#define HH 256
#define LN_EPS 1e-6f

typedef __attribute__((ext_vector_type(8))) short short8v;   // 8 bf16 (4 VGPRs)
typedef __attribute__((ext_vector_type(4))) float float4v;   // 4 fp32 acc

#define LDAH 264   // s_h1 leading dim in bf16 elems (528B: 16B-aligned)

#if __has_builtin(__builtin_amdgcn_exp2f)
#define EXP2F(x) __builtin_amdgcn_exp2f(x)
#else
#define EXP2F(x) exp2f(x)
#endif
#if __has_builtin(__builtin_amdgcn_sqrtf)
#define SQRTF(x) __builtin_amdgcn_sqrtf(x)
#else
#define SQRTF(x) sqrtf(x)
#endif

__device__ __forceinline__ float gelu_tanh(float x) {
    // 0.5x(1+tanh(c0(x+c1 x^3))) == x - x*rcp(1 + 2^(x*(a+b*x^2)))
    float x2 = x * x;
    float t  = __builtin_fmaf(0.10294340f, x2, 2.30211830f);
    float e  = EXP2F(x * t);
    float r  = __builtin_amdgcn_rcpf(e + 1.0f);
    return __builtin_fmaf(-x, r, x);
}

__device__ __forceinline__ unsigned short f2bf(float f) {
    unsigned u = __float_as_uint(f);
    unsigned r = u + 0x7fffu + ((u >> 16) & 1u);   // RNE
    return (unsigned short)(r >> 16);
}

// order-preserving float->uint for atomicMax pooling; enc(x) > 0x80000000 >= ... for
// any non-NaN x>=-0.0; zero-init (written by prep) is always beaten for finite vals.
__device__ __forceinline__ unsigned enc_f(float f) {
    unsigned b = __float_as_uint(f);
    return (b & 0x80000000u) ? ~b : (b | 0x80000000u);
}
__device__ __forceinline__ float dec_f(unsigned u) {
    return __uint_as_float((u & 0x80000000u) ? (u ^ 0x80000000u) : ~u);
}

// ---------------- Kernel 1: merged prep ----------------
// [0,1024): Aq/Ak ; [1024,1280): vproj + ctx init (0 or ln1_b) ;
// [1280,1536): Wa2T (+ block 1280 zeroes pooled) ;
// [1536,2560): per-bq compaction -> klist + FIXED-SLOT worklist (8 entries/bq, nv=0 = skip)
__global__ __launch_bounds__(256) void prep_kernel(
    const float* __restrict__ qs, const float* __restrict__ ks,
    const float* __restrict__ vs,
    const float* __restrict__ Wa1, const float* __restrict__ ba1,
    const float* __restrict__ Wv,  const float* __restrict__ bv,
    const float* __restrict__ Wa2,
    const float* __restrict__ qs_t, const float* __restrict__ ks_t,
    const int*   __restrict__ valid_lens,
    const float* __restrict__ ln1_b,
    float* __restrict__ Aq, float* __restrict__ Ak,
    float* __restrict__ vproj, unsigned short* __restrict__ Wa2T,
    int* __restrict__ klist, int* __restrict__ wl,
    unsigned* __restrict__ pooled,
    float* __restrict__ ctx_init) {
    __shared__ int s_cnt[8];
    __shared__ int s_off[9];
    const int bid = blockIdx.x;
    const int t   = threadIdx.x;
    if (bid < 1024) {
        int idx = bid * 256 + t;                   // over B*N*H
        int j  = idx & (HH - 1);
        int bn = idx >> 8;
        const float* qrow = qs + bn * FF;
        const float* krow = ks + bn * FF;
        float aq = ba1[j];
        float ak = 0.0f;
#pragma unroll 8
        for (int f = 0; f < FF; ++f) {
            aq += qrow[f] * Wa1[f * HH + j];
            ak += krow[f] * Wa1[(FF + f) * HH + j];
        }
        Aq[idx] = aq;
        Ak[idx] = ak;
    } else if (bid < 1280) {
        int idx = (bid - 1024) * 256 + t;          // over B*N*64
        int d  = idx & 63;
        int bn = idx >> 6;
        const float* vrow = vs + bn * FF;
        float a = bv[d];
#pragma unroll 8
        for (int f = 0; f < FF; ++f) a += vrow[f] * Wv[f * 64 + d];
        vproj[idx] = a;
        // ctx accumulator init: valid q -> 0 ; invalid q -> LN1(0-vector) = ln1_b
        int q = bn & 511;
        int b = bn >> 9;
        ctx_init[idx] = (q < valid_lens[b]) ? 0.0f : ln1_b[d];
    } else if (bid < 1536) {
        if (bid == 1280 && t < 128) pooled[t] = 0u;   // zero atomicMax targets
        int idx = (bid - 1280) * 256 + t;          // idx = n*256 + i
        int n = idx >> 8;
        int i = idx & 255;
        Wa2T[idx] = f2bf(Wa2[i * HH + n]);
    } else {
        // ---- compaction for bq = bid-1536 ----
        const int bq = bid - 1536;
        const int b  = bq >> 9;
        const int q  = bq & 511;
        if (q >= valid_lens[b]) {
            if (t < 8) wl[bq * 8 + t] = bq | (t << 10);   // nv=0: skip entries
            return;
        }
        const float qt = qs_t[bq];
        const int lane = t & 63;
        const int w    = t >> 6;
        bool validr[2];
        int  posr[2];
#pragma unroll
        for (int r = 0; r < 2; ++r) {
            int k = r * 256 + t;
            float kt = ks_t[b * NN + k];
            bool valid = (qt - kt) > 0.0f;
            unsigned long long bal = __ballot(valid);
            validr[r] = valid;
            posr[r] = (int)__popcll(bal & ((1ull << lane) - 1ull));
            if (lane == 0) s_cnt[r * 4 + w] = (int)__popcll(bal);
        }
        __syncthreads();
        if (t == 0) {
            int acc = 0;
#pragma unroll
            for (int i = 0; i < 8; ++i) { s_off[i] = acc; acc += s_cnt[i]; }
            s_off[8] = acc;
        }
        __syncthreads();
#pragma unroll
        for (int r = 0; r < 2; ++r)
            if (validr[r])
                klist[bq * 512 + s_off[r * 4 + w] + posr[r]] = r * 256 + t;
        const int nk = s_off[8];
        if (t < 8) {
            int nv = nk - (t << 6);
            nv = nv < 0 ? 0 : (nv > 64 ? 64 : nv);
            wl[bq * 8 + t] = bq | (t << 10) | (nv << 13);
        }
    }
}

// ---------------- Kernel 2: one worklist slot per block (STRAIGHT-LINE body) ----------------
// R5-R7 lesson: a multi-item loop in this body generates ~450 MB of scratch
// save/restore HBM traffic. One item per block (R4/R8 structure) is clean.
__global__ __launch_bounds__(256, 3) void attn_ctx_kernel(
    const float* __restrict__ ks_s, const float* __restrict__ qs_s,
    const float* __restrict__ qs_t, const float* __restrict__ ks_t,
    const float* __restrict__ Wa1,
    const unsigned short* __restrict__ Wa2T,
    const float* __restrict__ ba2, const float* __restrict__ Wa3,
    const float* __restrict__ ba3,
    const float* __restrict__ Aq,  const float* __restrict__ Ak,
    const float* __restrict__ vproj,
    const int* __restrict__ klist, const int* __restrict__ wl,
    float* __restrict__ ctx_acc_g) {

    __shared__ unsigned short s_h1[64 * LDAH];     // 33792 B
    __shared__ float4 s_feat4[64];
    __shared__ int    s_koe[64];
    __shared__ int    s_kvo[64];
    __shared__ float  s_part[4 * 64];
    __shared__ float  s_attn[64];

    const int e  = wl[blockIdx.x];
    const int nv = (e >> 13) & 127;
    if (nv == 0) return;                            // cheap uniform exit
    const int bq = e & 1023;
    const int c  = (e >> 10) & 7;
    const int b  = bq >> 9;

    const int t    = threadIdx.x;
    const int lane = t & 63;
    const int w    = t >> 6;
    const int l15  = lane & 15;
    const int quad = lane >> 4;

    // ---- pre-issue B-frags for ks=0 (drain under staging/h1) ----
    const int n0 = w * 64;
    const unsigned short* bbase = Wa2T + (size_t)(n0 + l15) * HH + quad * 8;
    short8v Bcur[4];
#pragma unroll
    for (int nt = 0; nt < 4; ++nt)
        Bcur[nt] = *(const short8v*)(bbase + (size_t)nt * 16 * HH);

    // ---- staging: k indices, features, offsets (threads 0..63) ----
    const float qt   = qs_t[bq];
    const float qss0 = qs_s[bq * 2 + 0];
    const float qss1 = qs_s[bq * 2 + 1];
    if (t < 64) {
        int k = klist[bq * 512 + c * 64 + ((t < nv) ? t : 0)];
        int bk = b * NN + k;
        float d0 = qss0 - ks_s[bk * 2 + 0];
        float d1 = qss1 - ks_s[bk * 2 + 1];
        float dist = SQRTF(d0 * d0 + d1 * d1);
        float td = qt - ks_t[bk];
        s_feat4[t] = make_float4(d0, d1, dist, td);
        s_koe[t] = bk * HH;
        s_kvo[t] = bk * 64;
    }
    __syncthreads();                                // B1

    // ---- h1 phase, j-pair layout: thread owns (j0,j0+1) x 32 kl ----
    // 16-deep float2 gather pipelining (longest-latency phase)
    {
        const int jp = (t & 127) * 2;               // even j
        const int kh = (t >> 7) * 32;               // kl half: 0 or 32
        const float2 aqv = *(const float2*)(Aq + bq * HH + jp);
        const float2 w0v = *(const float2*)(Wa1 + 128 * HH + jp);
        const float2 w1v = *(const float2*)(Wa1 + 129 * HH + jp);
        const float2 w2v = *(const float2*)(Wa1 + 130 * HH + jp);
        const float2 w3v = *(const float2*)(Wa1 + 131 * HH + jp);
        const float2 w4v = *(const float2*)(Wa1 + 132 * HH + jp);
        const float* __restrict__ Akj = Ak + jp;
        unsigned* __restrict__ s_h1w = (unsigned*)s_h1;
        const int colw = t & 127;                   // dword column
#pragma unroll
        for (int g = 0; g < 2; ++g) {
            float2 akv[16];
#pragma unroll
            for (int u = 0; u < 16; ++u)            // 16 independent float2 gathers
                akv[u] = *(const float2*)(Akj + s_koe[kh + g * 16 + u]);
#pragma unroll
            for (int u = 0; u < 16; ++u) {
                const int kl = kh + g * 16 + u;
                float4 f = s_feat4[kl];
                float fz2 = f.z * f.z;
                float v0 = aqv.x + akv[u].x + w0v.x * f.x + w1v.x * f.y
                         + w2v.x * f.z + w3v.x * fz2 + w4v.x * f.w;
                float v1 = aqv.y + akv[u].y + w0v.y * f.x + w1v.y * f.y
                         + w2v.y * f.z + w3v.y * fz2 + w4v.y * f.w;
                unsigned lo = f2bf(gelu_tanh(v0));
                unsigned hi = f2bf(gelu_tanh(v1));
                s_h1w[kl * (LDAH / 2) + colw] = lo | (hi << 16);
            }
        }
    }
    __syncthreads();                                // B2

    // ---- MFMA GEMM 64x256 @ Wa2T (wave w: cols n0..n0+63), rolling B prefetch ----
    float4v acc[4][4];
#pragma unroll
    for (int mt = 0; mt < 4; ++mt)
#pragma unroll
        for (int nt = 0; nt < 4; ++nt) acc[mt][nt] = (float4v){0.f, 0.f, 0.f, 0.f};
    const unsigned short* abase = s_h1 + l15 * LDAH + quad * 8;
#pragma unroll
    for (int ksx = 0; ksx < 8; ++ksx) {
        short8v Bnxt[4];
        if (ksx < 7) {
            const int k1 = (ksx + 1) * 32;
#pragma unroll
            for (int nt = 0; nt < 4; ++nt)
                Bnxt[nt] = *(const short8v*)(bbase + (size_t)nt * 16 * HH + k1);
        }
        short8v Af[4];
        const int k0 = ksx * 32;
#pragma unroll
        for (int mt = 0; mt < 4; ++mt)
            Af[mt] = *(const short8v*)(abase + mt * 16 * LDAH + k0);
#pragma unroll
        for (int mt = 0; mt < 4; ++mt)
#pragma unroll
            for (int nt = 0; nt < 4; ++nt)
                acc[mt][nt] = __builtin_amdgcn_mfma_f32_16x16x32_bf16(
                    Af[mt], Bcur[nt], acc[mt][nt], 0, 0, 0);
        if (ksx < 7) {
#pragma unroll
            for (int nt = 0; nt < 4; ++nt) Bcur[nt] = Bnxt[nt];
        }
    }

    // ---- epilogue: h2 = gelu(acc+ba2), dot Wa3, reduce over 16 cols/quad ----
    {
        float ba2r[4], wa3r[4];
#pragma unroll
        for (int nt = 0; nt < 4; ++nt) {
            int col = n0 + nt * 16 + l15;
            ba2r[nt] = ba2[col];
            wa3r[nt] = Wa3[col];
        }
        float prow[4][4];
#pragma unroll
        for (int mt = 0; mt < 4; ++mt)
#pragma unroll
            for (int r = 0; r < 4; ++r) prow[mt][r] = 0.0f;
#pragma unroll
        for (int mt = 0; mt < 4; ++mt)
#pragma unroll
            for (int nt = 0; nt < 4; ++nt)
#pragma unroll
                for (int r = 0; r < 4; ++r)
                    prow[mt][r] += gelu_tanh(acc[mt][nt][r] + ba2r[nt]) * wa3r[nt];
#pragma unroll
        for (int m = 1; m < 16; m <<= 1)
#pragma unroll
            for (int mt = 0; mt < 4; ++mt)
#pragma unroll
                for (int r = 0; r < 4; ++r)
                    prow[mt][r] += __shfl_xor(prow[mt][r], m);
        if (l15 == 0) {
#pragma unroll
            for (int mt = 0; mt < 4; ++mt)
#pragma unroll
                for (int r = 0; r < 4; ++r)
                    s_part[w * 64 + mt * 16 + quad * 4 + r] = prow[mt][r];
        }
    }
    __syncthreads();                                // B3

    if (t < 64) {
        float a = 0.0f;
        if (t < nv)
            a = s_part[t] + s_part[64 + t] + s_part[128 + t] + s_part[192 + t] + ba3[0];
        s_attn[t] = a;
    }
    __syncthreads();                                // B4

    // ---- ctx partial across all 4 waves: wave w handles kl = w*16..w*16+15 ----
    {
        float vv[16];
#pragma unroll
        for (int u = 0; u < 16; ++u)                // 16 independent gathers
            vv[u] = vproj[s_kvo[w * 16 + u] + lane];
        float cacc = 0.0f;
#pragma unroll
        for (int u = 0; u < 16; ++u)
            cacc += s_attn[w * 16 + u] * vv[u];
        s_part[w * 64 + lane] = cacc;
    }
    __syncthreads();                                // B5
    if (t < 64) {
        float v = s_part[t] + s_part[64 + t] + s_part[128 + t] + s_part[192 + t];
        atomicAdd(&ctx_acc_g[bq * 64 + t], v);
    }
}

// ---------------- Kernel 3: LN1 (valid q only) + gate MLP ; masked max -> pooled ----------------
__global__ __launch_bounds__(256) void gate_kernel(
    float* __restrict__ ctx,                        // in: raw sums, out: normalized
    const float* __restrict__ ln1_s, const float* __restrict__ ln1_b,
    const float* __restrict__ Wg1, const float* __restrict__ bg1,
    const float* __restrict__ Wg2, const float* __restrict__ bg2,
    const int* __restrict__ valid_lens,
    unsigned* __restrict__ pooled) {
    __shared__ float s_ctx[64];
    __shared__ float s_hg[256];
    const int t  = threadIdx.x;
    const int bq = blockIdx.x;
    const int b  = bq >> 9;
    const int q  = bq & 511;
    if (q >= valid_lens[b]) return;                 // invalid q: ctx = ln1_b written by prep
    if (t < 64) {                                   // wave 0: LN1
        float x = ctx[bq * 64 + t];
        float s = x;
#pragma unroll
        for (int m = 1; m < 64; m <<= 1) s += __shfl_xor(s, m);
        float mu = s * (1.0f / 64.0f);
        float dv = x - mu;
        float vv = dv * dv;
#pragma unroll
        for (int m = 1; m < 64; m <<= 1) vv += __shfl_xor(vv, m);
        float rs = rsqrtf(vv * (1.0f / 64.0f) + LN_EPS);
        float y = dv * rs * ln1_s[t] + ln1_b[t];
        ctx[bq * 64 + t] = y;
        s_ctx[t] = y;
    }
    __syncthreads();
    float a = bg1[t];
#pragma unroll 8
    for (int d = 0; d < 64; ++d) a += s_ctx[d] * Wg1[d * 256 + t];
    s_hg[t] = gelu_tanh(a);
    __syncthreads();
    if (t < 64) {
        float g = bg2[t];
#pragma unroll 8
        for (int jj = 0; jj < 256; ++jj) g += s_hg[jj] * Wg2[jj * 64 + t];
        atomicMax(&pooled[b * 64 + t], enc_f(g * s_ctx[t]));
    }
}

// ---------------- Kernel 4: vnode = LN2(pooled) ----------------
__global__ __launch_bounds__(64) void ln2_kernel(
    const unsigned* __restrict__ pooled,
    const float* __restrict__ ln2_s, const float* __restrict__ ln2_b,
    float* __restrict__ vnode_out) {
    const int t = threadIdx.x;
    const int b = blockIdx.x;
    float x = dec_f(pooled[b * 64 + t]);
    float s = x;
#pragma unroll
    for (int mm = 1; mm < 64; mm <<= 1) s += __shfl_xor(s, mm);
    float mu = s * (1.0f / 64.0f);
    float dv = x - mu;
    float vv = dv * dv;
#pragma unroll
    for (int mm = 1; mm < 64; mm <<= 1) vv += __shfl_xor(vv, mm);
    float rs = rsqrtf(vv * (1.0f / 64.0f) + LN_EPS);
    vnode_out[b * 64 + t] = dv * rs * ln2_s[t] + ln2_b[t];
}

extern "C" void kernel_launch(void* const* d_in, const int* in_sizes, int n_in,
                              void* d_out, int out_size, void* d_ws, size_t ws_size,
                              hipStream_t stream) {
    const float* qs   = (const float*)d_in[0];
    const float* ks   = (const float*)d_in[1];
    const float* vs   = (const float*)d_in[2];
    const float* qs_s = (const float*)d_in[3];
    const float* ks_s = (const float*)d_in[4];
    const float* qs_t = (const float*)d_in[5];
    const float* ks_t = (const float*)d_in[6];
    const int*   valid_lens = (const int*)d_in[7];
    const float* Wv   = (const float*)d_in[8];
    const float* bv   = (const float*)d_in[9];
    const float* Wa1  = (const float*)d_in[10];
    const float* ba1  = (const float*)d_in[11];
    const float* Wa2  = (const float*)d_in[12];
    const float* ba2  = (const float*)d_in[13];
    const float* Wa3  = (const float*)d_in[14];
    const float* ba3  = (const float*)d_in[15];
    const float* Wg1  = (const float*)d_in[16];
    const float* bg1  = (const float*)d_in[17];
    const float* Wg2  = (const float*)d_in[18];
    const float* bg2  = (const float*)d_in[19];
    const float* ln1_s = (const float*)d_in[20];
    const float* ln1_b = (const float*)d_in[21];
    const float* ln2_s = (const float*)d_in[22];
    const float* ln2_b = (const float*)d_in[23];

    float* out = (float*)d_out;                     // [0,65536): ctx ; [65536,65664): vnode
    float* ws  = (float*)d_ws;
    float* Aq    = ws;                              // 262144 f
    float* Ak    = Aq + BB * NN * HH;               // 262144 f
    float* vproj = Ak + BB * NN * HH;               // 65536 f
    unsigned short* Wa2T = (unsigned short*)(vproj + BB * NN * 64);   // 65536 bf16
    int* klist = (int*)(Wa2T + HH * HH);            // 524288 int
    unsigned* pooled = (unsigned*)(klist + BB * NN * 512);  // 128
    int* wl = (int*)(pooled + 128);                 // 8192 fixed slots

    prep_kernel<<<2560, 256, 0, stream>>>(qs, ks, vs, Wa1, ba1, Wv, bv, Wa2,
                                          qs_t, ks_t, valid_lens, ln1_b,
                                          Aq, Ak, vproj, Wa2T, klist, wl, pooled, out);
    attn_ctx_kernel<<<8192, 256, 0, stream>>>(ks_s, qs_s, qs_t, ks_t,
                                              Wa1, Wa2T, ba2, Wa3, ba3,
                                              Aq, Ak, vproj,
                                              klist, wl, out);
    gate_kernel<<<BB * NN, 256, 0, stream>>>(out, ln1_s, ln1_b, Wg1, bg1, Wg2, bg2,
                                             valid_lens, pooled);
    ln2_kernel<<<BB, 64, 0, stream>>>(pooled, ln2_s, ln2_b, out + BB * NN * 64);
}

// Round 11
// 205.039 us; speedup vs baseline: 1.1976x; 1.1976x over previous
//
#include <hip/hip_runtime.h>
#include <math.h>

#define BB 2
#define NN 512
#define FF 64
#define HH 256
#define LN_EPS 1e-6f

typedef __attribute__((ext_vector_type(8))) short short8v;   // 8 bf16 (4 VGPRs)
typedef __attribute__((ext_vector_type(4))) float float4v;   // 4 fp32 acc

#define LDAH 264   // s_h1 leading dim in bf16 elems (528B: 16B-aligned)

#if __has_builtin(__builtin_amdgcn_exp2f)
#define EXP2F(x) __builtin_amdgcn_exp2f(x)
#else
#define EXP2F(x) exp2f(x)
#endif
#if __has_builtin(__builtin_amdgcn_sqrtf)
#define SQRTF(x) __builtin_amdgcn_sqrtf(x)
#else
#define SQRTF(x) sqrtf(x)
#endif

__device__ __forceinline__ float gelu_tanh(float x) {
    // 0.5x(1+tanh(c0(x+c1 x^3))) == x - x*rcp(1 + 2^(x*(a+b*x^2)))
    float x2 = x * x;
    float t  = __builtin_fmaf(0.10294340f, x2, 2.30211830f);
    float e  = EXP2F(x * t);
    float r  = __builtin_amdgcn_rcpf(e + 1.0f);
    return __builtin_fmaf(-x, r, x);
}

__device__ __forceinline__ unsigned short f2bf(float f) {
    unsigned u = __float_as_uint(f);
    unsigned r = u + 0x7fffu + ((u >> 16) & 1u);   // RNE
    return (unsigned short)(r >> 16);
}

// order-preserving float->uint for atomicMax pooling
__device__ __forceinline__ unsigned enc_f(float f) {
    unsigned b = __float_as_uint(f);
    return (b & 0x80000000u) ? ~b : (b | 0x80000000u);
}
__device__ __forceinline__ float dec_f(unsigned u) {
    return __uint_as_float((u & 0x80000000u) ? (u ^ 0x80000000u) : ~u);
}

// ---------------- Kernel 1: merged prep ----------------
// [0,1024): Aq/Ak ; [1024,1280): vproj + ctx init (0 or ln1_b) ;
// [1280,1536): Wa2T (+ block 1280 zeroes pooled) ;
// [1536,2560): per-bq compaction -> klist + DENSE worklist (atomic append — real
// chunks front-packed in wl; R10 lesson: fixed-slot interleaving of empty entries
// starves the in-order dispatcher and halves attn occupancy)
__global__ __launch_bounds__(256) void prep_kernel(
    const float* __restrict__ qs, const float* __restrict__ ks,
    const float* __restrict__ vs,
    const float* __restrict__ Wa1, const float* __restrict__ ba1,
    const float* __restrict__ Wv,  const float* __restrict__ bv,
    const float* __restrict__ Wa2,
    const float* __restrict__ qs_t, const float* __restrict__ ks_t,
    const int*   __restrict__ valid_lens,
    const float* __restrict__ ln1_b,
    float* __restrict__ Aq, float* __restrict__ Ak,
    float* __restrict__ vproj, unsigned short* __restrict__ Wa2T,
    int* __restrict__ klist, int* __restrict__ wl_count, int* __restrict__ wl,
    unsigned* __restrict__ pooled,
    float* __restrict__ ctx_init) {
    __shared__ int s_cnt[8];
    __shared__ int s_off[9];
    const int bid = blockIdx.x;
    const int t   = threadIdx.x;
    if (bid < 1024) {
        int idx = bid * 256 + t;                   // over B*N*H
        int j  = idx & (HH - 1);
        int bn = idx >> 8;
        const float* qrow = qs + bn * FF;
        const float* krow = ks + bn * FF;
        float aq = ba1[j];
        float ak = 0.0f;
#pragma unroll 8
        for (int f = 0; f < FF; ++f) {
            aq += qrow[f] * Wa1[f * HH + j];
            ak += krow[f] * Wa1[(FF + f) * HH + j];
        }
        Aq[idx] = aq;
        Ak[idx] = ak;
    } else if (bid < 1280) {
        int idx = (bid - 1024) * 256 + t;          // over B*N*64
        int d  = idx & 63;
        int bn = idx >> 6;
        const float* vrow = vs + bn * FF;
        float a = bv[d];
#pragma unroll 8
        for (int f = 0; f < FF; ++f) a += vrow[f] * Wv[f * 64 + d];
        vproj[idx] = a;
        // ctx accumulator init: valid q -> 0 ; invalid q -> LN1(0-vector) = ln1_b
        int q = bn & 511;
        int b = bn >> 9;
        ctx_init[idx] = (q < valid_lens[b]) ? 0.0f : ln1_b[d];
    } else if (bid < 1536) {
        if (bid == 1280 && t < 128) pooled[t] = 0u;   // zero atomicMax targets
        int idx = (bid - 1280) * 256 + t;          // idx = n*256 + i
        int n = idx >> 8;
        int i = idx & 255;
        Wa2T[idx] = f2bf(Wa2[i * HH + n]);
    } else {
        // ---- compaction for bq = bid-1536 ----
        const int bq = bid - 1536;
        const int b  = bq >> 9;
        const int q  = bq & 511;
        if (q >= valid_lens[b]) return;            // no entries for invalid q
        const float qt = qs_t[bq];
        const int lane = t & 63;
        const int w    = t >> 6;
        bool validr[2];
        int  posr[2];
#pragma unroll
        for (int r = 0; r < 2; ++r) {
            int k = r * 256 + t;
            float kt = ks_t[b * NN + k];
            bool valid = (qt - kt) > 0.0f;
            unsigned long long bal = __ballot(valid);
            validr[r] = valid;
            posr[r] = (int)__popcll(bal & ((1ull << lane) - 1ull));
            if (lane == 0) s_cnt[r * 4 + w] = (int)__popcll(bal);
        }
        __syncthreads();
        if (t == 0) {
            int acc = 0;
#pragma unroll
            for (int i = 0; i < 8; ++i) { s_off[i] = acc; acc += s_cnt[i]; }
            s_off[8] = acc;
        }
        __syncthreads();
#pragma unroll
        for (int r = 0; r < 2; ++r)
            if (validr[r])
                klist[bq * 512 + s_off[r * 4 + w] + posr[r]] = r * 256 + t;
        const int nk = s_off[8];
        if (t == 0 && nk > 0) {
            int nch = (nk + 63) >> 6;
            int base = atomicAdd(wl_count, nch);
            for (int c = 0; c < nch; ++c) {
                int nv = nk - (c << 6);
                nv = nv > 64 ? 64 : nv;
                wl[base + c] = bq | (c << 10) | (nv << 13);
            }
        }
    }
}

// ---------------- Kernel 2: one worklist entry per block (STRAIGHT-LINE body) ----------------
// R5-R7 lesson: a multi-item loop in this body generates ~450 MB of scratch
// save/restore HBM traffic. One item per block (R4/R8/R9 structure) is clean.
__global__ __launch_bounds__(256, 3) void attn_ctx_kernel(
    const float* __restrict__ ks_s, const float* __restrict__ qs_s,
    const float* __restrict__ qs_t, const float* __restrict__ ks_t,
    const float* __restrict__ Wa1,
    const unsigned short* __restrict__ Wa2T,
    const float* __restrict__ ba2, const float* __restrict__ Wa3,
    const float* __restrict__ ba3,
    const float* __restrict__ Aq,  const float* __restrict__ Ak,
    const float* __restrict__ vproj,
    const int* __restrict__ klist, const int* __restrict__ wl_count,
    const int* __restrict__ wl,
    float* __restrict__ ctx_acc_g) {

    __shared__ unsigned short s_h1[64 * LDAH];     // 33792 B
    __shared__ float4 s_feat4[64];
    __shared__ int    s_koe[64];
    __shared__ int    s_kvo[64];
    __shared__ float  s_part[4 * 64];
    __shared__ float  s_attn[64];

    const int i = blockIdx.x;
    if (i >= wl_count[0]) return;                   // cheap uniform exit (dense tail)

    const int t    = threadIdx.x;
    const int lane = t & 63;
    const int w    = t >> 6;
    const int l15  = lane & 15;
    const int quad = lane >> 4;

    const int e  = wl[i];
    const int bq = e & 1023;
    const int c  = (e >> 10) & 7;
    const int nv = (e >> 13) & 127;
    const int b  = bq >> 9;

    // ---- pre-issue B-frags for ks=0 (drain under staging/h1) ----
    const int n0 = w * 64;
    const unsigned short* bbase = Wa2T + (size_t)(n0 + l15) * HH + quad * 8;
    short8v Bcur[4];
#pragma unroll
    for (int nt = 0; nt < 4; ++nt)
        Bcur[nt] = *(const short8v*)(bbase + (size_t)nt * 16 * HH);

    // ---- staging: k indices, features, offsets (threads 0..63) ----
    const float qt   = qs_t[bq];
    const float qss0 = qs_s[bq * 2 + 0];
    const float qss1 = qs_s[bq * 2 + 1];
    if (t < 64) {
        int k = klist[bq * 512 + c * 64 + ((t < nv) ? t : 0)];
        int bk = b * NN + k;
        float d0 = qss0 - ks_s[bk * 2 + 0];
        float d1 = qss1 - ks_s[bk * 2 + 1];
        float dist = SQRTF(d0 * d0 + d1 * d1);
        float td = qt - ks_t[bk];
        s_feat4[t] = make_float4(d0, d1, dist, td);
        s_koe[t] = bk * HH;
        s_kvo[t] = bk * 64;
    }
    __syncthreads();                                // B1

    // ---- h1 phase, j-pair layout: thread owns (j0,j0+1) x 32 kl ----
    // Ak gathers as float2 (half the loads), packed b32 LDS writes, 8-deep pipelining
    {
        const int jp = (t & 127) * 2;               // even j
        const int kh = (t >> 7) * 32;               // kl half: 0 or 32
        const float2 aqv = *(const float2*)(Aq + bq * HH + jp);
        const float2 w0v = *(const float2*)(Wa1 + 128 * HH + jp);
        const float2 w1v = *(const float2*)(Wa1 + 129 * HH + jp);
        const float2 w2v = *(const float2*)(Wa1 + 130 * HH + jp);
        const float2 w3v = *(const float2*)(Wa1 + 131 * HH + jp);
        const float2 w4v = *(const float2*)(Wa1 + 132 * HH + jp);
        const float* __restrict__ Akj = Ak + jp;
        unsigned* __restrict__ s_h1w = (unsigned*)s_h1;
        const int colw = t & 127;                   // dword column
#pragma unroll
        for (int g = 0; g < 4; ++g) {
            float2 akv[8];
#pragma unroll
            for (int u = 0; u < 8; ++u)             // 8 independent float2 gathers
                akv[u] = *(const float2*)(Akj + s_koe[kh + g * 8 + u]);
#pragma unroll
            for (int u = 0; u < 8; ++u) {
                const int kl = kh + g * 8 + u;
                float4 f = s_feat4[kl];
                float fz2 = f.z * f.z;
                float v0 = aqv.x + akv[u].x + w0v.x * f.x + w1v.x * f.y
                         + w2v.x * f.z + w3v.x * fz2 + w4v.x * f.w;
                float v1 = aqv.y + akv[u].y + w0v.y * f.x + w1v.y * f.y
                         + w2v.y * f.z + w3v.y * fz2 + w4v.y * f.w;
                unsigned lo = f2bf(gelu_tanh(v0));
                unsigned hi = f2bf(gelu_tanh(v1));
                s_h1w[kl * (LDAH / 2) + colw] = lo | (hi << 16);
            }
        }
    }
    __syncthreads();                                // B2

    // ---- MFMA GEMM 64x256 @ Wa2T (wave w: cols n0..n0+63), rolling B prefetch ----
    float4v acc[4][4];
#pragma unroll
    for (int mt = 0; mt < 4; ++mt)
#pragma unroll
        for (int nt = 0; nt < 4; ++nt) acc[mt][nt] = (float4v){0.f, 0.f, 0.f, 0.f};
    const unsigned short* abase = s_h1 + l15 * LDAH + quad * 8;
#pragma unroll
    for (int ksx = 0; ksx < 8; ++ksx) {
        short8v Bnxt[4];
        if (ksx < 7) {
            const int k1 = (ksx + 1) * 32;
#pragma unroll
            for (int nt = 0; nt < 4; ++nt)
                Bnxt[nt] = *(const short8v*)(bbase + (size_t)nt * 16 * HH + k1);
        }
        short8v Af[4];
        const int k0 = ksx * 32;
#pragma unroll
        for (int mt = 0; mt < 4; ++mt)
            Af[mt] = *(const short8v*)(abase + mt * 16 * LDAH + k0);
#pragma unroll
        for (int mt = 0; mt < 4; ++mt)
#pragma unroll
            for (int nt = 0; nt < 4; ++nt)
                acc[mt][nt] = __builtin_amdgcn_mfma_f32_16x16x32_bf16(
                    Af[mt], Bcur[nt], acc[mt][nt], 0, 0, 0);
        if (ksx < 7) {
#pragma unroll
            for (int nt = 0; nt < 4; ++nt) Bcur[nt] = Bnxt[nt];
        }
    }

    // ---- epilogue: h2 = gelu(acc+ba2), dot Wa3, reduce over 16 cols/quad ----
    {
        float ba2r[4], wa3r[4];
#pragma unroll
        for (int nt = 0; nt < 4; ++nt) {
            int col = n0 + nt * 16 + l15;
            ba2r[nt] = ba2[col];
            wa3r[nt] = Wa3[col];
        }
        float prow[4][4];
#pragma unroll
        for (int mt = 0; mt < 4; ++mt)
#pragma unroll
            for (int r = 0; r < 4; ++r) prow[mt][r] = 0.0f;
#pragma unroll
        for (int mt = 0; mt < 4; ++mt)
#pragma unroll
            for (int nt = 0; nt < 4; ++nt)
#pragma unroll
                for (int r = 0; r < 4; ++r)
                    prow[mt][r] += gelu_tanh(acc[mt][nt][r] + ba2r[nt]) * wa3r[nt];
#pragma unroll
        for (int m = 1; m < 16; m <<= 1)
#pragma unroll
            for (int mt = 0; mt < 4; ++mt)
#pragma unroll
                for (int r = 0; r < 4; ++r)
                    prow[mt][r] += __shfl_xor(prow[mt][r], m);
        if (l15 == 0) {
#pragma unroll
            for (int mt = 0; mt < 4; ++mt)
#pragma unroll
                for (int r = 0; r < 4; ++r)
                    s_part[w * 64 + mt * 16 + quad * 4 + r] = prow[mt][r];
        }
    }
    __syncthreads();                                // B3

    if (t < 64) {
        float a = 0.0f;
        if (t < nv)
            a = s_part[t] + s_part[64 + t] + s_part[128 + t] + s_part[192 + t] + ba3[0];
        s_attn[t] = a;
    }
    __syncthreads();                                // B4

    // ---- ctx partial across all 4 waves: wave w handles kl = w*16..w*16+15 ----
    {
        float cacc = 0.0f;
#pragma unroll
        for (int g = 0; g < 2; ++g) {
            float vv[8];
#pragma unroll
            for (int u = 0; u < 8; ++u)
                vv[u] = vproj[s_kvo[w * 16 + g * 8 + u] + lane];
#pragma unroll
            for (int u = 0; u < 8; ++u)
                cacc += s_attn[w * 16 + g * 8 + u] * vv[u];
        }
        s_part[w * 64 + lane] = cacc;
    }
    __syncthreads();                                // B5
    if (t < 64) {
        float v = s_part[t] + s_part[64 + t] + s_part[128 + t] + s_part[192 + t];
        atomicAdd(&ctx_acc_g[bq * 64 + t], v);
    }
}

// ---------------- Kernel 3: LN1 (valid q only) + gate MLP ; masked max -> pooled ----------------
__global__ __launch_bounds__(256) void gate_kernel(
    float* __restrict__ ctx,                        // in: raw sums, out: normalized
    const float* __restrict__ ln1_s, const float* __restrict__ ln1_b,
    const float* __restrict__ Wg1, const float* __restrict__ bg1,
    const float* __restrict__ Wg2, const float* __restrict__ bg2,
    const int* __restrict__ valid_lens,
    unsigned* __restrict__ pooled) {
    __shared__ float s_ctx[64];
    __shared__ float s_hg[256];
    const int t  = threadIdx.x;
    const int bq = blockIdx.x;
    const int b  = bq >> 9;
    const int q  = bq & 511;
    if (q >= valid_lens[b]) return;                 // invalid q: ctx = ln1_b written by prep
    if (t < 64) {                                   // wave 0: LN1
        float x = ctx[bq * 64 + t];
        float s = x;
#pragma unroll
        for (int m = 1; m < 64; m <<= 1) s += __shfl_xor(s, m);
        float mu = s * (1.0f / 64.0f);
        float dv = x - mu;
        float vv = dv * dv;
#pragma unroll
        for (int m = 1; m < 64; m <<= 1) vv += __shfl_xor(vv, m);
        float rs = rsqrtf(vv * (1.0f / 64.0f) + LN_EPS);
        float y = dv * rs * ln1_s[t] + ln1_b[t];
        ctx[bq * 64 + t] = y;
        s_ctx[t] = y;
    }
    __syncthreads();
    float a = bg1[t];
#pragma unroll 8
    for (int d = 0; d < 64; ++d) a += s_ctx[d] * Wg1[d * 256 + t];
    s_hg[t] = gelu_tanh(a);
    __syncthreads();
    if (t < 64) {
        float g = bg2[t];
#pragma unroll 8
        for (int jj = 0; jj < 256; ++jj) g += s_hg[jj] * Wg2[jj * 64 + t];
        atomicMax(&pooled[b * 64 + t], enc_f(g * s_ctx[t]));
    }
}

// ---------------- Kernel 4: vnode = LN2(pooled) ----------------
__global__ __launch_bounds__(64) void ln2_kernel(
    const unsigned* __restrict__ pooled,
    const float* __restrict__ ln2_s, const float* __restrict__ ln2_b,
    float* __restrict__ vnode_out) {
    const int t = threadIdx.x;
    const int b = blockIdx.x;
    float x = dec_f(pooled[b * 64 + t]);
    float s = x;
#pragma unroll
    for (int mm = 1; mm < 64; mm <<= 1) s += __shfl_xor(s, mm);
    float mu = s * (1.0f / 64.0f);
    float dv = x - mu;
    float vv = dv * dv;
#pragma unroll
    for (int mm = 1; mm < 64; mm <<= 1) vv += __shfl_xor(vv, mm);
    float rs = rsqrtf(vv * (1.0f / 64.0f) + LN_EPS);
    vnode_out[b * 64 + t] = dv * rs * ln2_s[t] + ln2_b[t];
}

extern "C" void kernel_launch(void* const* d_in, const int* in_sizes, int n_in,
                              void* d_out, int out_size, void* d_ws, size_t ws_size,
                              hipStream_t stream) {
    const float* qs   = (const float*)d_in[0];
    const float* ks   = (const float*)d_in[1];
    const float* vs   = (const float*)d_in[2];
    const float* qs_s = (const float*)d_in[3];
    const float* ks_s = (const float*)d_in[4];
    const float* qs_t = (const float*)d_in[5];
    const float* ks_t = (const float*)d_in[6];
    const int*   valid_lens = (const int*)d_in[7];
    const float* Wv   = (const float*)d_in[8];
    const float* bv   = (const float*)d_in[9];
    const float* Wa1  = (const float*)d_in[10];
    const float* ba1  = (const float*)d_in[11];
    const float* Wa2  = (const float*)d_in[12];
    const float* ba2  = (const float*)d_in[13];
    const float* Wa3  = (const float*)d_in[14];
    const float* ba3  = (const float*)d_in[15];
    const float* Wg1  = (const float*)d_in[16];
    const float* bg1  = (const float*)d_in[17];
    const float* Wg2  = (const float*)d_in[18];
    const float* bg2  = (const float*)d_in[19];
    const float* ln1_s = (const float*)d_in[20];
    const float* ln1_b = (const float*)d_in[21];
    const float* ln2_s = (const float*)d_in[22];
    const float* ln2_b = (const float*)d_in[23];

    float* out = (float*)d_out;                     // [0,65536): ctx ; [65536,65664): vnode
    float* ws  = (float*)d_ws;
    float* Aq    = ws;                              // 262144 f
    float* Ak    = Aq + BB * NN * HH;               // 262144 f
    float* vproj = Ak + BB * NN * HH;               // 65536 f
    unsigned short* Wa2T = (unsigned short*)(vproj + BB * NN * 64);   // 65536 bf16
    int* klist = (int*)(Wa2T + HH * HH);            // 524288 int
    int* wl_count = klist + BB * NN * 512;          // 1 (padded 64)
    unsigned* pooled = (unsigned*)(wl_count + 64);  // 128
    int* wl = (int*)(pooled + 128);                 // up to 8192 (dense)

    hipMemsetAsync(wl_count, 0, 64 * sizeof(int), stream);
    prep_kernel<<<2560, 256, 0, stream>>>(qs, ks, vs, Wa1, ba1, Wv, bv, Wa2,
                                          qs_t, ks_t, valid_lens, ln1_b,
                                          Aq, Ak, vproj, Wa2T, klist, wl_count, wl,
                                          pooled, out);
    attn_ctx_kernel<<<8192, 256, 0, stream>>>(ks_s, qs_s, qs_t, ks_t,
                                              Wa1, Wa2T, ba2, Wa3, ba3,
                                              Aq, Ak, vproj,
                                              klist, wl_count, wl, out);
    gate_kernel<<<BB * NN, 256, 0, stream>>>(out, ln1_s, ln1_b, Wg1, bg1, Wg2, bg2,
                                             valid_lens, pooled);
    ln2_kernel<<<BB, 64, 0, stream>>>(pooled, ln2_s, ln2_b, out + BB * NN * 64);
}

// Round 12
// 199.623 us; speedup vs baseline: 1.2301x; 1.0271x over previous
//
#include <hip/hip_runtime.h>
#include <math.h>

#define BB 2
#define NN 512
#define FF 64
#define HH 256
#define LN_EPS 1e-6f

typedef __attribute__((ext_vector_type(8))) short short8v;   // 8 bf16 (4 VGPRs)
typedef __attribute__((ext_vector_type(4))) float float4v;   // 4 fp32 acc

#define LDAH 264   // s_h1 leading dim in bf16 elems (528B: 16B-aligned)

#if __has_builtin(__builtin_amdgcn_exp2f)
#define EXP2F(x) __builtin_amdgcn_exp2f(x)
#else
#define EXP2F(x) exp2f(x)
#endif
#if __has_builtin(__builtin_amdgcn_sqrtf)
#define SQRTF(x) __builtin_amdgcn_sqrtf(x)
#else
#define SQRTF(x) sqrtf(x)
#endif

__device__ __forceinline__ float gelu_tanh(float x) {
    // 0.5x(1+tanh(c0(x+c1 x^3))) == x - x*rcp(1 + 2^(x*(a+b*x^2)))
    float x2 = x * x;
    float t  = __builtin_fmaf(0.10294340f, x2, 2.30211830f);
    float e  = EXP2F(x * t);
    float r  = __builtin_amdgcn_rcpf(e + 1.0f);
    return __builtin_fmaf(-x, r, x);
}

__device__ __forceinline__ unsigned short f2bf(float f) {
    unsigned u = __float_as_uint(f);
    unsigned r = u + 0x7fffu + ((u >> 16) & 1u);   // RNE
    return (unsigned short)(r >> 16);
}

// order-preserving float->uint for atomicMax pooling
__device__ __forceinline__ unsigned enc_f(float f) {
    unsigned b = __float_as_uint(f);
    return (b & 0x80000000u) ? ~b : (b | 0x80000000u);
}
__device__ __forceinline__ float dec_f(unsigned u) {
    return __uint_as_float((u & 0x80000000u) ? (u ^ 0x80000000u) : ~u);
}

// ---------------- Kernel 1: merged prep ----------------
// [0,1024): Aq/Ak ; [1024,1280): vproj + ctx init (0 or ln1_b) ;
// [1280,1536): Wa2T (+ block 1280 zeroes pooled) ;
// [1536,2560): per-bq compaction -> flist {d0,d1,td,bits(k)} + DENSE worklist
// (atomic append — R10 lesson: interleaved empty slots starve the in-order
// dispatcher; dense front-packing is required)
__global__ __launch_bounds__(256) void prep_kernel(
    const float* __restrict__ qs, const float* __restrict__ ks,
    const float* __restrict__ vs,
    const float* __restrict__ Wa1, const float* __restrict__ ba1,
    const float* __restrict__ Wv,  const float* __restrict__ bv,
    const float* __restrict__ Wa2,
    const float* __restrict__ qs_s, const float* __restrict__ ks_s,
    const float* __restrict__ qs_t, const float* __restrict__ ks_t,
    const int*   __restrict__ valid_lens,
    const float* __restrict__ ln1_b,
    float* __restrict__ Aq, float* __restrict__ Ak,
    float* __restrict__ vproj, unsigned short* __restrict__ Wa2T,
    float4* __restrict__ flist, int* __restrict__ wl_count, int* __restrict__ wl,
    unsigned* __restrict__ pooled,
    float* __restrict__ ctx_init) {
    __shared__ int s_cnt[8];
    __shared__ int s_off[9];
    const int bid = blockIdx.x;
    const int t   = threadIdx.x;
    if (bid < 1024) {
        int idx = bid * 256 + t;                   // over B*N*H
        int j  = idx & (HH - 1);
        int bn = idx >> 8;
        const float* qrow = qs + bn * FF;
        const float* krow = ks + bn * FF;
        float aq = ba1[j];
        float ak = 0.0f;
#pragma unroll 8
        for (int f = 0; f < FF; ++f) {
            aq += qrow[f] * Wa1[f * HH + j];
            ak += krow[f] * Wa1[(FF + f) * HH + j];
        }
        Aq[idx] = aq;
        Ak[idx] = ak;
    } else if (bid < 1280) {
        int idx = (bid - 1024) * 256 + t;          // over B*N*64
        int d  = idx & 63;
        int bn = idx >> 6;
        const float* vrow = vs + bn * FF;
        float a = bv[d];
#pragma unroll 8
        for (int f = 0; f < FF; ++f) a += vrow[f] * Wv[f * 64 + d];
        vproj[idx] = a;
        // ctx accumulator init: valid q -> 0 ; invalid q -> LN1(0-vector) = ln1_b
        int q = bn & 511;
        int b = bn >> 9;
        ctx_init[idx] = (q < valid_lens[b]) ? 0.0f : ln1_b[d];
    } else if (bid < 1536) {
        if (bid == 1280 && t < 128) pooled[t] = 0u;   // zero atomicMax targets
        int idx = (bid - 1280) * 256 + t;          // idx = n*256 + i
        int n = idx >> 8;
        int i = idx & 255;
        Wa2T[idx] = f2bf(Wa2[i * HH + n]);
    } else {
        // ---- compaction for bq = bid-1536 ----
        const int bq = bid - 1536;
        const int b  = bq >> 9;
        const int q  = bq & 511;
        if (q >= valid_lens[b]) return;            // no entries for invalid q
        const float qt   = qs_t[bq];
        const float qss0 = qs_s[bq * 2 + 0];
        const float qss1 = qs_s[bq * 2 + 1];
        const int lane = t & 63;
        const int w    = t >> 6;
        bool validr[2];
        int  posr[2];
        float ktr[2];
        float2 ksr[2];
#pragma unroll
        for (int r = 0; r < 2; ++r) {
            int k = r * 256 + t;
            float kt = ks_t[b * NN + k];
            ksr[r] = *(const float2*)(ks_s + (b * NN + k) * 2);  // coalesced
            ktr[r] = kt;
            bool valid = (qt - kt) > 0.0f;
            unsigned long long bal = __ballot(valid);
            validr[r] = valid;
            posr[r] = (int)__popcll(bal & ((1ull << lane) - 1ull));
            if (lane == 0) s_cnt[r * 4 + w] = (int)__popcll(bal);
        }
        __syncthreads();
        if (t == 0) {
            int acc = 0;
#pragma unroll
            for (int i = 0; i < 8; ++i) { s_off[i] = acc; acc += s_cnt[i]; }
            s_off[8] = acc;
        }
        __syncthreads();
#pragma unroll
        for (int r = 0; r < 2; ++r)
            if (validr[r]) {
                int gpos = s_off[r * 4 + w] + posr[r];
                float d0 = qss0 - ksr[r].x;
                float d1 = qss1 - ksr[r].y;
                float td = qt - ktr[r];
                flist[bq * 512 + gpos] =
                    make_float4(d0, d1, td, __int_as_float(r * 256 + t));
            }
        const int nk = s_off[8];
        if (t == 0 && nk > 0) {
            int nch = (nk + 63) >> 6;
            int base = atomicAdd(wl_count, nch);
            for (int c = 0; c < nch; ++c) {
                int nv = nk - (c << 6);
                nv = nv > 64 ? 64 : nv;
                wl[base + c] = bq | (c << 10) | (nv << 13);
            }
        }
    }
}

// ---------------- Kernel 2: one worklist entry per block (STRAIGHT-LINE body) ----------------
// R5-R7 lesson: a multi-item loop in this body generates ~450 MB of scratch
// save/restore HBM traffic. One item per block is clean. wl is pre-zeroed, so
// tail blocks read one entry (nv=0) and exit — no wl_count on the critical path.
__global__ __launch_bounds__(256, 3) void attn_ctx_kernel(
    const float* __restrict__ Wa1,
    const unsigned short* __restrict__ Wa2T,
    const float* __restrict__ ba2, const float* __restrict__ Wa3,
    const float* __restrict__ ba3,
    const float* __restrict__ Aq,  const float* __restrict__ Ak,
    const float* __restrict__ vproj,
    const float4* __restrict__ flist, const int* __restrict__ wl,
    float* __restrict__ ctx_acc_g) {

    __shared__ unsigned short s_h1[64 * LDAH];     // 33792 B
    __shared__ float4 s_feat4[64];                 // {d0, d1, dist, td}
    __shared__ int    s_koe[64];
    __shared__ int    s_kvo[64];
    __shared__ float  s_part[4 * 64];
    __shared__ float  s_attn[64];

    const int e  = wl[blockIdx.x];
    const int nv = (e >> 13) & 127;
    if (nv == 0) return;                            // zero-filled tail -> exit
    const int bq = e & 1023;
    const int c  = (e >> 10) & 7;
    const int b  = bq >> 9;

    const int t    = threadIdx.x;
    const int lane = t & 63;
    const int w    = t >> 6;
    const int l15  = lane & 15;
    const int quad = lane >> 4;

    // ---- pre-issue B-frags for ks=0 + h1-phase row constants (drain under staging) ----
    const int n0 = w * 64;
    const unsigned short* bbase = Wa2T + (size_t)(n0 + l15) * HH + quad * 8;
    short8v Bcur[4];
#pragma unroll
    for (int nt = 0; nt < 4; ++nt)
        Bcur[nt] = *(const short8v*)(bbase + (size_t)nt * 16 * HH);

    const int jp = (t & 127) * 2;                   // even j (h1 phase)
    const float2 aqv = *(const float2*)(Aq + bq * HH + jp);
    const float2 w0v = *(const float2*)(Wa1 + 128 * HH + jp);
    const float2 w1v = *(const float2*)(Wa1 + 129 * HH + jp);
    const float2 w2v = *(const float2*)(Wa1 + 130 * HH + jp);
    const float2 w3v = *(const float2*)(Wa1 + 131 * HH + jp);
    const float2 w4v = *(const float2*)(Wa1 + 132 * HH + jp);

    // ---- staging: one coalesced b128 per lane (feats precomputed in prep) ----
    if (t < 64) {
        float4 f = flist[bq * 512 + c * 64 + ((t < nv) ? t : 0)];
        int k = __float_as_int(f.w);
        int bk = b * NN + k;
        float dist = SQRTF(f.x * f.x + f.y * f.y);
        s_feat4[t] = make_float4(f.x, f.y, dist, f.z);
        s_koe[t] = bk * HH;
        s_kvo[t] = bk * 64;
    }
    __syncthreads();                                // B1

    // ---- h1 phase, j-pair layout: thread owns (j0,j0+1) x 32 kl, 16-deep gathers ----
    {
        const int kh = (t >> 7) * 32;               // kl half: 0 or 32
        const float* __restrict__ Akj = Ak + jp;
        unsigned* __restrict__ s_h1w = (unsigned*)s_h1;
        const int colw = t & 127;                   // dword column
#pragma unroll
        for (int g = 0; g < 2; ++g) {
            float2 akv[16];
#pragma unroll
            for (int u = 0; u < 16; ++u)            // 16 independent float2 gathers
                akv[u] = *(const float2*)(Akj + s_koe[kh + g * 16 + u]);
#pragma unroll
            for (int u = 0; u < 16; ++u) {
                const int kl = kh + g * 16 + u;
                float4 f = s_feat4[kl];
                float fz2 = f.z * f.z;
                float v0 = aqv.x + akv[u].x + w0v.x * f.x + w1v.x * f.y
                         + w2v.x * f.z + w3v.x * fz2 + w4v.x * f.w;
                float v1 = aqv.y + akv[u].y + w0v.y * f.x + w1v.y * f.y
                         + w2v.y * f.z + w3v.y * fz2 + w4v.y * f.w;
                unsigned lo = f2bf(gelu_tanh(v0));
                unsigned hi = f2bf(gelu_tanh(v1));
                s_h1w[kl * (LDAH / 2) + colw] = lo | (hi << 16);
            }
        }
    }
    __syncthreads();                                // B2

    // ---- MFMA GEMM 64x256 @ Wa2T (wave w: cols n0..n0+63), rolling B prefetch ----
    float4v acc[4][4];
#pragma unroll
    for (int mt = 0; mt < 4; ++mt)
#pragma unroll
        for (int nt = 0; nt < 4; ++nt) acc[mt][nt] = (float4v){0.f, 0.f, 0.f, 0.f};
    const unsigned short* abase = s_h1 + l15 * LDAH + quad * 8;

    float ba2r[4], wa3r[4];                         // epilogue constants: issue early
#pragma unroll
    for (int nt = 0; nt < 4; ++nt) {
        int col = n0 + nt * 16 + l15;
        ba2r[nt] = ba2[col];
        wa3r[nt] = Wa3[col];
    }

#pragma unroll
    for (int ksx = 0; ksx < 8; ++ksx) {
        short8v Bnxt[4];
        if (ksx < 7) {
            const int k1 = (ksx + 1) * 32;
#pragma unroll
            for (int nt = 0; nt < 4; ++nt)
                Bnxt[nt] = *(const short8v*)(bbase + (size_t)nt * 16 * HH + k1);
        }
        short8v Af[4];
        const int k0 = ksx * 32;
#pragma unroll
        for (int mt = 0; mt < 4; ++mt)
            Af[mt] = *(const short8v*)(abase + mt * 16 * LDAH + k0);
#pragma unroll
        for (int mt = 0; mt < 4; ++mt)
#pragma unroll
            for (int nt = 0; nt < 4; ++nt)
                acc[mt][nt] = __builtin_amdgcn_mfma_f32_16x16x32_bf16(
                    Af[mt], Bcur[nt], acc[mt][nt], 0, 0, 0);
        if (ksx < 7) {
#pragma unroll
            for (int nt = 0; nt < 4; ++nt) Bcur[nt] = Bnxt[nt];
        }
    }

    // ---- epilogue: h2 = gelu(acc+ba2), dot Wa3, reduce over 16 cols/quad ----
    {
        float prow[4][4];
#pragma unroll
        for (int mt = 0; mt < 4; ++mt)
#pragma unroll
            for (int r = 0; r < 4; ++r) prow[mt][r] = 0.0f;
#pragma unroll
        for (int mt = 0; mt < 4; ++mt)
#pragma unroll
            for (int nt = 0; nt < 4; ++nt)
#pragma unroll
                for (int r = 0; r < 4; ++r)
                    prow[mt][r] += gelu_tanh(acc[mt][nt][r] + ba2r[nt]) * wa3r[nt];
#pragma unroll
        for (int m = 1; m < 16; m <<= 1)
#pragma unroll
            for (int mt = 0; mt < 4; ++mt)
#pragma unroll
                for (int r = 0; r < 4; ++r)
                    prow[mt][r] += __shfl_xor(prow[mt][r], m);
        if (l15 == 0) {
#pragma unroll
            for (int mt = 0; mt < 4; ++mt)
#pragma unroll
                for (int r = 0; r < 4; ++r)
                    s_part[w * 64 + mt * 16 + quad * 4 + r] = prow[mt][r];
        }
    }
    __syncthreads();                                // B3

    if (t < 64) {
        float a = 0.0f;
        if (t < nv)
            a = s_part[t] + s_part[64 + t] + s_part[128 + t] + s_part[192 + t] + ba3[0];
        s_attn[t] = a;
    }
    __syncthreads();                                // B4

    // ---- ctx partial across all 4 waves: wave w handles kl = w*16..w*16+15 ----
    {
        float vv[16];
#pragma unroll
        for (int u = 0; u < 16; ++u)                // 16 independent gathers
            vv[u] = vproj[s_kvo[w * 16 + u] + lane];
        float cacc = 0.0f;
#pragma unroll
        for (int u = 0; u < 16; ++u)
            cacc += s_attn[w * 16 + u] * vv[u];
        s_part[w * 64 + lane] = cacc;
    }
    __syncthreads();                                // B5
    if (t < 64) {
        float v = s_part[t] + s_part[64 + t] + s_part[128 + t] + s_part[192 + t];
        atomicAdd(&ctx_acc_g[bq * 64 + t], v);
    }
}

// ---------------- Kernel 3: LN1 (valid q only) + gate MLP ; masked max -> pooled ----------------
__global__ __launch_bounds__(256) void gate_kernel(
    float* __restrict__ ctx,                        // in: raw sums, out: normalized
    const float* __restrict__ ln1_s, const float* __restrict__ ln1_b,
    const float* __restrict__ Wg1, const float* __restrict__ bg1,
    const float* __restrict__ Wg2, const float* __restrict__ bg2,
    const int* __restrict__ valid_lens,
    unsigned* __restrict__ pooled) {
    __shared__ float s_ctx[64];
    __shared__ float s_hg[256];
    __shared__ float s_p2[256];
    const int t  = threadIdx.x;
    const int bq = blockIdx.x;
    const int b  = bq >> 9;
    const int q  = bq & 511;
    if (q >= valid_lens[b]) return;                 // invalid q: ctx = ln1_b written by prep
    if (t < 64) {                                   // wave 0: LN1
        float x = ctx[bq * 64 + t];
        float s = x;
#pragma unroll
        for (int m = 1; m < 64; m <<= 1) s += __shfl_xor(s, m);
        float mu = s * (1.0f / 64.0f);
        float dv = x - mu;
        float vv = dv * dv;
#pragma unroll
        for (int m = 1; m < 64; m <<= 1) vv += __shfl_xor(vv, m);
        float rs = rsqrtf(vv * (1.0f / 64.0f) + LN_EPS);
        float y = dv * rs * ln1_s[t] + ln1_b[t];
        ctx[bq * 64 + t] = y;
        s_ctx[t] = y;
    }
    __syncthreads();
    float a = bg1[t];
#pragma unroll 8
    for (int d = 0; d < 64; ++d) a += s_ctx[d] * Wg1[d * 256 + t];
    s_hg[t] = gelu_tanh(a);
    __syncthreads();
    {
        // phase 2 split across all 256 threads: seg owns 64 jj's
        const int d = t & 63, seg = t >> 6;
        const float* hg = s_hg + seg * 64;
        const float* w2 = Wg2 + seg * 64 * 64 + d;
        float g = 0.0f;
#pragma unroll 8
        for (int jj = 0; jj < 64; ++jj) g += hg[jj] * w2[jj * 64];
        s_p2[t] = g;
    }
    __syncthreads();
    if (t < 64) {
        float g = bg2[t] + s_p2[t] + s_p2[64 + t] + s_p2[128 + t] + s_p2[192 + t];
        atomicMax(&pooled[b * 64 + t], enc_f(g * s_ctx[t]));
    }
}

// ---------------- Kernel 4: vnode = LN2(pooled) ----------------
__global__ __launch_bounds__(64) void ln2_kernel(
    const unsigned* __restrict__ pooled,
    const float* __restrict__ ln2_s, const float* __restrict__ ln2_b,
    float* __restrict__ vnode_out) {
    const int t = threadIdx.x;
    const int b = blockIdx.x;
    float x = dec_f(pooled[b * 64 + t]);
    float s = x;
#pragma unroll
    for (int mm = 1; mm < 64; mm <<= 1) s += __shfl_xor(s, mm);
    float mu = s * (1.0f / 64.0f);
    float dv = x - mu;
    float vv = dv * dv;
#pragma unroll
    for (int mm = 1; mm < 64; mm <<= 1) vv += __shfl_xor(vv, mm);
    float rs = rsqrtf(vv * (1.0f / 64.0f) + LN_EPS);
    vnode_out[b * 64 + t] = dv * rs * ln2_s[t] + ln2_b[t];
}

extern "C" void kernel_launch(void* const* d_in, const int* in_sizes, int n_in,
                              void* d_out, int out_size, void* d_ws, size_t ws_size,
                              hipStream_t stream) {
    const float* qs   = (const float*)d_in[0];
    const float* ks   = (const float*)d_in[1];
    const float* vs   = (const float*)d_in[2];
    const float* qs_s = (const float*)d_in[3];
    const float* ks_s = (const float*)d_in[4];
    const float* qs_t = (const float*)d_in[5];
    const float* ks_t = (const float*)d_in[6];
    const int*   valid_lens = (const int*)d_in[7];
    const float* Wv   = (const float*)d_in[8];
    const float* bv   = (const float*)d_in[9];
    const float* Wa1  = (const float*)d_in[10];
    const float* ba1  = (const float*)d_in[11];
    const float* Wa2  = (const float*)d_in[12];
    const float* ba2  = (const float*)d_in[13];
    const float* Wa3  = (const float*)d_in[14];
    const float* ba3  = (const float*)d_in[15];
    const float* Wg1  = (const float*)d_in[16];
    const float* bg1  = (const float*)d_in[17];
    const float* Wg2  = (const float*)d_in[18];
    const float* bg2  = (const float*)d_in[19];
    const float* ln1_s = (const float*)d_in[20];
    const float* ln1_b = (const float*)d_in[21];
    const float* ln2_s = (const float*)d_in[22];
    const float* ln2_b = (const float*)d_in[23];

    float* out = (float*)d_out;                     // [0,65536): ctx ; [65536,65664): vnode
    float* ws  = (float*)d_ws;
    float* Aq    = ws;                              // 262144 f (1 MB)
    float* Ak    = Aq + BB * NN * HH;               // 262144 f (1 MB)
    float* vproj = Ak + BB * NN * HH;               // 65536 f (256 KB)
    unsigned short* Wa2T = (unsigned short*)(vproj + BB * NN * 64);   // 128 KB
    int* wl_count = (int*)(Wa2T + HH * HH);         // 64 ints
    int* wl       = wl_count + 64;                  // 8192 ints (zeroed)
    unsigned* pooled = (unsigned*)(wl + 8192);      // 128
    float4* flist = (float4*)(pooled + 128);        // B*N*512 float4 (8 MB)

    // zero wl_count + wl (contiguous 8256 ints): enables count-free attn exit
    hipMemsetAsync(wl_count, 0, (64 + 8192) * sizeof(int), stream);
    prep_kernel<<<2560, 256, 0, stream>>>(qs, ks, vs, Wa1, ba1, Wv, bv, Wa2,
                                          qs_s, ks_s, qs_t, ks_t, valid_lens, ln1_b,
                                          Aq, Ak, vproj, Wa2T, flist, wl_count, wl,
                                          pooled, out);
    attn_ctx_kernel<<<8192, 256, 0, stream>>>(Wa1, Wa2T, ba2, Wa3, ba3,
                                              Aq, Ak, vproj,
                                              flist, wl, out);
    gate_kernel<<<BB * NN, 256, 0, stream>>>(out, ln1_s, ln1_b, Wg1, bg1, Wg2, bg2,
                                             valid_lens, pooled);
    ln2_kernel<<<BB, 64, 0, stream>>>(pooled, ln2_s, ln2_b, out + BB * NN * 64);
}